// Round 5
// baseline (1724.953 us; speedup 1.0000x reference)
//
#include <hip/hip_runtime.h>

using u16 = unsigned short;

// ---------- bf16 <-> fp32 helpers ----------
__device__ __forceinline__ float bf2f(u16 u) {
  return __uint_as_float(((unsigned)u) << 16);
}
__device__ __forceinline__ u16 f2bf(float f) {
  unsigned u = __float_as_uint(f);
  u += 0x7FFFu + ((u >> 16) & 1u);  // RNE
  return (u16)(u >> 16);
}

// ---------- raw-input loaders: *flag==1 -> fp32, else bf16 ----------
__device__ __forceinline__ float ldr(const void* __restrict__ p, size_t i, int f) {
  return f ? ((const float*)p)[i] : bf2f(((const u16*)p)[i]);
}
__device__ __forceinline__ void ldr4(const void* __restrict__ p, size_t i, int f,
                                     float* o) {
  if (f) {
    float4 v = *reinterpret_cast<const float4*>((const float*)p + i);
    o[0] = v.x; o[1] = v.y; o[2] = v.z; o[3] = v.w;
  } else {
    ushort4 u = *reinterpret_cast<const ushort4*>((const u16*)p + i);
    o[0] = bf2f(u.x); o[1] = bf2f(u.y); o[2] = bf2f(u.z); o[3] = bf2f(u.w);
  }
}

// ---------- dtype detect: temperature==1.0 -> bf16 word0 = 0x3F80; fp32 word0 = 0x0000
__global__ void detect_dtype(const u16* __restrict__ t, int* __restrict__ flag) {
  if (threadIdx.x == 0) { flag[0] = (t[0] == 0x3F80u) ? 0 : 1; flag[1] = 0; }
}

// ---------- GEMM: C[b](64-tile) = A[aRow0+.., K] * B[b](KxN) ----------
// grid (M/64, N/64, batch), block 256. A,B raw (flag-dispatched). TC = u16 (bf16) or float.
template <typename TC>
__global__ __launch_bounds__(256) void gemm_raw(
    const void* __restrict__ A, int aRow0, const void* __restrict__ B,
    TC* __restrict__ C, int N, int K,
    const int* __restrict__ fA, const int* __restrict__ fB) {
  const int fa = *fA, fb = *fB;
  __shared__ float As[16][64];
  __shared__ float Bs[16][64];
  const int t = threadIdx.x;
  const int tx = t & 15, ty = t >> 4;
  const int bm = blockIdx.x * 64, bn = blockIdx.y * 64;
  const size_t bb = blockIdx.z;
  const int am = t >> 2, ak = (t & 3) * 4;
  const int bk = t >> 4, bn4 = (t & 15) * 4;
  float acc[4][4] = {};
  for (int k0 = 0; k0 < K; k0 += 16) {
    float ta[4], tb[4];
    ldr4(A, (size_t)(aRow0 + bm + am) * K + (k0 + ak), fa, ta);
    ldr4(B, bb * (size_t)K * N + (size_t)(k0 + bk) * N + (bn + bn4), fb, tb);
    As[ak + 0][am] = ta[0]; As[ak + 1][am] = ta[1];
    As[ak + 2][am] = ta[2]; As[ak + 3][am] = ta[3];
    *reinterpret_cast<float4*>(&Bs[bk][bn4]) = make_float4(tb[0], tb[1], tb[2], tb[3]);
    __syncthreads();
#pragma unroll
    for (int kk = 0; kk < 16; ++kk) {
      float4 av = *reinterpret_cast<const float4*>(&As[kk][ty * 4]);
      float4 bv = *reinterpret_cast<const float4*>(&Bs[kk][tx * 4]);
      float a[4] = {av.x, av.y, av.z, av.w};
      float b[4] = {bv.x, bv.y, bv.z, bv.w};
#pragma unroll
      for (int i = 0; i < 4; ++i)
#pragma unroll
        for (int j = 0; j < 4; ++j) acc[i][j] += a[i] * b[j];
    }
    __syncthreads();
  }
  TC* Cb = C + bb * (size_t)gridDim.x * 64 * N;
#pragma unroll
  for (int i = 0; i < 4; ++i) {
    TC* p = Cb + (size_t)(bm + ty * 4 + i) * N + (bn + tx * 4);
    if constexpr (sizeof(TC) == 2) {
      ushort4 u = make_ushort4(f2bf(acc[i][0]), f2bf(acc[i][1]),
                               f2bf(acc[i][2]), f2bf(acc[i][3]));
      *reinterpret_cast<ushort4*>(p) = u;
    } else {
      *reinterpret_cast<float4*>(p) =
          make_float4(acc[i][0], acc[i][1], acc[i][2], acc[i][3]);
    }
  }
}

// ---------- full 3x3 conv on 32x32 maps; W raw, X bf16, C bf16 ----------
__global__ __launch_bounds__(256) void conv3x3_full(
    const void* __restrict__ W, const u16* __restrict__ X, u16* __restrict__ C,
    const int* __restrict__ fW) {
  const int fw = *fW;
  __shared__ float As[16][64];
  __shared__ float Bs[16][64];
  const int t = threadIdx.x;
  const int tx = t & 15, ty = t >> 4;
  const int bm = blockIdx.x * 64, bn = blockIdx.y * 64;
  const size_t bb = blockIdx.z;
  const u16* Xb = X + bb * (size_t)(384 * 1024);
  const int am = t >> 2, ak = (t & 3) * 4;
  const int bk = t >> 4, bn4 = (t & 15) * 4;
  float acc[4][4] = {};
  for (int tap = 0; tap < 9; ++tap) {
    const int dy = tap / 3 - 1, dx = tap % 3 - 1;
    for (int k0 = 0; k0 < 384; k0 += 16) {
#pragma unroll
      for (int e = 0; e < 4; ++e)
        As[ak + e][am] =
            ldr(W, (size_t)(bm + am) * 3456 + (size_t)(k0 + ak + e) * 9 + tap, fw);
      const u16* Xr = Xb + (size_t)(k0 + bk) * 1024;
#pragma unroll
      for (int e = 0; e < 4; ++e) {
        int n = bn + bn4 + e;
        int r = (n >> 5) + dy, c = (n & 31) + dx;
        Bs[bk][bn4 + e] =
            (r >= 0 && r < 32 && c >= 0 && c < 32) ? bf2f(Xr[r * 32 + c]) : 0.f;
      }
      __syncthreads();
#pragma unroll
      for (int kk = 0; kk < 16; ++kk) {
        float4 av = *reinterpret_cast<const float4*>(&As[kk][ty * 4]);
        float4 bv = *reinterpret_cast<const float4*>(&Bs[kk][tx * 4]);
        float a[4] = {av.x, av.y, av.z, av.w};
        float b[4] = {bv.x, bv.y, bv.z, bv.w};
#pragma unroll
        for (int i = 0; i < 4; ++i)
#pragma unroll
          for (int j = 0; j < 4; ++j) acc[i][j] += a[i] * b[j];
      }
      __syncthreads();
    }
  }
  u16* Cb = C + bb * (size_t)(384 * 1024);
#pragma unroll
  for (int i = 0; i < 4; ++i) {
    ushort4 u = make_ushort4(f2bf(acc[i][0]), f2bf(acc[i][1]),
                             f2bf(acc[i][2]), f2bf(acc[i][3]));
    *reinterpret_cast<ushort4*>(Cb + (size_t)(bm + ty * 4 + i) * 1024 + (bn + tx * 4)) = u;
  }
}

// ---------- depthwise 3x3, full res; src (8,384,4096) bf16 -> dst bf16 ----------
__global__ __launch_bounds__(256) void dw_full(
    const u16* __restrict__ src, const void* __restrict__ wdw, int wRow0,
    u16* __restrict__ dst, const int* __restrict__ fW) {
  const int fw = *fW;
  int idx = blockIdx.x * 256 + threadIdx.x;   // (b*384+c)*4096 + p
  int p = idx & 4095;
  int bc = idx >> 12;
  int c = bc % 384;
  int yy = p >> 6, xx = p & 63;
  const u16* s0 = src + (size_t)bc * 4096;
  float w[9];
#pragma unroll
  for (int i = 0; i < 9; ++i) w[i] = ldr(wdw, (size_t)(wRow0 + c) * 9 + i, fw);
  float s = 0.f;
#pragma unroll
  for (int dy = -1; dy <= 1; ++dy)
#pragma unroll
    for (int dx = -1; dx <= 1; ++dx) {
      int Y = yy + dy, X = xx + dx;
      if (Y >= 0 && Y < 64 && X >= 0 && X < 64)
        s += w[(dy + 1) * 3 + (dx + 1)] * bf2f(s0[Y * 64 + X]);
    }
  dst[idx] = f2bf(s);
}

// ---------- depthwise 3x3 fused with 2x2 mean pool; src (8,384,4096) bf16 ----------
__global__ __launch_bounds__(256) void dw_pool(
    const u16* __restrict__ src, const void* __restrict__ wdw, int wRow0,
    u16* __restrict__ dst, const int* __restrict__ fW) {
  const int fw = *fW;
  int idx = blockIdx.x * 256 + threadIdx.x;   // (b*384+c)*1024 + pp
  int pp = idx & 1023;
  int bc = idx >> 10;
  int c = bc % 384;
  int py = pp >> 5, px = pp & 31;
  const u16* s0 = src + (size_t)bc * 4096;
  float w[9];
#pragma unroll
  for (int i = 0; i < 9; ++i) w[i] = ldr(wdw, (size_t)(wRow0 + c) * 9 + i, fw);
  float s = 0.f;
#pragma unroll
  for (int sy = 0; sy < 2; ++sy)
#pragma unroll
    for (int sx = 0; sx < 2; ++sx) {
      int yy = 2 * py + sy, xx = 2 * px + sx;
#pragma unroll
      for (int dy = -1; dy <= 1; ++dy)
#pragma unroll
        for (int dx = -1; dx <= 1; ++dx) {
          int Y = yy + dy, X = xx + dx;
          if (Y >= 0 && Y < 64 && X >= 0 && X < 64)
            s += w[(dy + 1) * 3 + (dx + 1)] * bf2f(s0[Y * 64 + X]);
        }
    }
  dst[idx] = f2bf(s * 0.25f);
}

// ---------- L2 norms of 1024-length bf16 rows ----------
__global__ __launch_bounds__(256) void rownorm(
    const u16* __restrict__ q3, const u16* __restrict__ kp,
    float* __restrict__ qn, float* __restrict__ kn) {
  const u16* X = (blockIdx.y == 0 ? q3 : kp) + (size_t)blockIdx.x * 1024;
  int t = threadIdx.x;
  ushort4 u = reinterpret_cast<const ushort4*>(X)[t];
  float a = bf2f(u.x), b = bf2f(u.y), c = bf2f(u.z), d = bf2f(u.w);
  float s = a * a + b * b + c * c + d * d;
#pragma unroll
  for (int off = 32; off > 0; off >>= 1) s += __shfl_down(s, off, 64);
  __shared__ float red[4];
  if ((t & 63) == 0) red[t >> 6] = s;
  __syncthreads();
  if (t == 0) {
    float tot = red[0] + red[1] + red[2] + red[3];
    (blockIdx.y == 0 ? qn : kn)[blockIdx.x] = sqrtf(tot);
  }
}

// ---------- attention scores + softmax, one block per (b,h) ----------
__global__ __launch_bounds__(256) void attn_sm(
    const u16* __restrict__ q, const u16* __restrict__ kpool,
    const float* __restrict__ qn, const float* __restrict__ kn,
    const void* __restrict__ temp, const int* __restrict__ fT,
    float* __restrict__ attn) {
  const int ft = *fT;
  __shared__ float qs[48][129];
  __shared__ float ks[48][129];
  __shared__ float at[48][48];
  int bh = blockIdx.x;
  int b = bh >> 3, h = bh & 7;
  int t = threadIdx.x;
  int i0 = (t >> 4) * 3, j0 = (t & 15) * 3;
  const u16* qb = q + ((size_t)b * 384 + h * 48) * 1024;
  const u16* kb = kpool + ((size_t)b * 384 + h * 48) * 1024;
  float acc[3][3] = {};
  for (int n0 = 0; n0 < 1024; n0 += 128) {
    for (int e = t; e < 48 * 32; e += 256) {   // 48 rows x 32 ushort4 groups
      int row = e >> 5, col4 = (e & 31) * 4;
      ushort4 uq = *reinterpret_cast<const ushort4*>(qb + (size_t)row * 1024 + n0 + col4);
      ushort4 uk = *reinterpret_cast<const ushort4*>(kb + (size_t)row * 1024 + n0 + col4);
      qs[row][col4 + 0] = bf2f(uq.x); qs[row][col4 + 1] = bf2f(uq.y);
      qs[row][col4 + 2] = bf2f(uq.z); qs[row][col4 + 3] = bf2f(uq.w);
      ks[row][col4 + 0] = bf2f(uk.x); ks[row][col4 + 1] = bf2f(uk.y);
      ks[row][col4 + 2] = bf2f(uk.z); ks[row][col4 + 3] = bf2f(uk.w);
    }
    __syncthreads();
#pragma unroll 4
    for (int nn = 0; nn < 128; ++nn) {
      float q0 = qs[i0][nn], q1 = qs[i0 + 1][nn], q2 = qs[i0 + 2][nn];
      float k0 = ks[j0][nn], k1 = ks[j0 + 1][nn], k2 = ks[j0 + 2][nn];
      acc[0][0] += q0 * k0; acc[0][1] += q0 * k1; acc[0][2] += q0 * k2;
      acc[1][0] += q1 * k0; acc[1][1] += q1 * k1; acc[1][2] += q1 * k2;
      acc[2][0] += q2 * k0; acc[2][1] += q2 * k1; acc[2][2] += q2 * k2;
    }
    __syncthreads();
  }
  float tv = ldr(temp, h, ft);
#pragma unroll
  for (int ii = 0; ii < 3; ++ii)
#pragma unroll
    for (int jj = 0; jj < 3; ++jj) {
      int i = i0 + ii, j = j0 + jj;
      float sc = tv / (fmaxf(qn[b * 384 + h * 48 + i], 1e-12f) *
                       fmaxf(kn[b * 384 + h * 48 + j], 1e-12f));
      at[i][j] = acc[ii][jj] * sc;
    }
  __syncthreads();
  if (t < 48) {
    float mx = -3.4e38f;
#pragma unroll
    for (int j = 0; j < 48; ++j) mx = fmaxf(mx, at[t][j]);
    float sum = 0.f;
    float e[48];
#pragma unroll
    for (int j = 0; j < 48; ++j) { e[j] = expf(at[t][j] - mx); sum += e[j]; }
    float inv = 1.f / sum;
    float* ao = attn + (size_t)bh * 2304 + t * 48;
#pragma unroll
    for (int j = 0; j < 48; ++j) ao[j] = e[j] * inv;
  }
}

// ---------- aout = attn(48x48) @ v(48x4096) per (b,h); v/aout bf16 ----------
__global__ __launch_bounds__(256) void applyV(
    const float* __restrict__ attn, const u16* __restrict__ v, u16* __restrict__ out) {
  __shared__ float at[48][48];
  int bh = blockIdx.y;
  int t = threadIdx.x;
  for (int e = t; e < 2304; e += 256) at[e / 48][e % 48] = attn[(size_t)bh * 2304 + e];
  __syncthreads();
  int p = blockIdx.x * 256 + t;
  const u16* vb = v + (size_t)bh * 48 * 4096 + p;
  float acc[48] = {};
#pragma unroll
  for (int c4 = 0; c4 < 48; c4 += 4) {
    float v0 = bf2f(vb[(size_t)(c4 + 0) * 4096]);
    float v1 = bf2f(vb[(size_t)(c4 + 1) * 4096]);
    float v2 = bf2f(vb[(size_t)(c4 + 2) * 4096]);
    float v3 = bf2f(vb[(size_t)(c4 + 3) * 4096]);
#pragma unroll
    for (int c0 = 0; c0 < 48; ++c0) {
      float4 a = *reinterpret_cast<const float4*>(&at[c0][c4]);
      acc[c0] += a.x * v0 + a.y * v1 + a.z * v2 + a.w * v3;
    }
  }
  u16* ob = out + (size_t)bh * 48 * 4096 + p;
#pragma unroll
  for (int c0 = 0; c0 < 48; ++c0) ob[(size_t)c0 * 4096] = f2bf(acc[c0]);
}

extern "C" void kernel_launch(void* const* d_in, const int* in_sizes, int n_in,
                              void* d_out, int out_size, void* d_ws, size_t ws_size,
                              hipStream_t stream) {
  const void* x       = d_in[0];  // (8,384,64,64)
  const void* y       = d_in[1];  // (8,384,32,32)
  const void* w_kv    = d_in[2];  // (768,384)
  const void* w_kv_dw = d_in[3];  // (768,9)
  const void* w_q     = d_in[4];  // (384,384)
  const void* w_q_dw  = d_in[5];  // (384,384,3,3)
  const void* w_proj  = d_in[6];  // (384,384)
  const void* temp    = d_in[7];  // (8)
  float* out = (float*)d_out;     // fp32 output (12.6M floats = 50 MB)

  // ---- workspace: ~64 MB total, 256B-aligned slabs ----
  char* base = (char*)d_ws;
  size_t off = 0;
  auto alloc = [&](size_t bytes) {
    void* p = base + off;
    off += (bytes + 255) & ~(size_t)255;
    return p;
  };
  int*   flag = (int*)  alloc(8);              // flag[0]=detected, flag[1]=0 (bf16)
  float* qn   = (float*)alloc(3072ull * 4);
  float* kn   = (float*)alloc(3072ull * 4);
  float* attn = (float*)alloc(147456ull * 4);
  u16*   slabBig = (u16*)alloc(12582912ull * 2); // tmpV -> q3 -> aout (disjoint lifetimes)
  u16*   v    = (u16*)  alloc(12582912ull * 2);  // (8,384,4096)
  u16*   kp   = (u16*)  alloc(3145728ull * 2);   // (8,384,1024)
  u16*   q1   = (u16*)  alloc(3145728ull * 2);   // (8,384,1024)

  u16* khalf = (u16*)d_out;  // bf16 staging in d_out's first half (dead before final write)
  u16* tmpV  = slabBig;      // phase 1
  u16* q3    = slabBig;      // phase 2 (first 6.3 MB)
  u16* aout  = slabBig;      // phase 3 (full 25.2 MB)

  // 0) detect input dtype
  detect_dtype<<<1, 64, 0, stream>>>((const u16*)temp, flag);
  // 1) k-half: kv[:, :384] = W_kv[0:384] @ x  -> d_out staging (bf16)
  gemm_raw<u16><<<dim3(6, 64, 8), 256, 0, stream>>>(w_kv, 0, x, khalf, 4096, 384, flag, flag);
  // 2) dw 3x3 + 2x2 mean pool on k-half -> kp
  dw_pool<<<dim3(12288), 256, 0, stream>>>(khalf, w_kv_dw, 0, kp, flag);
  // 3) v-half: kv[:, 384:] = W_kv[384:768] @ x -> tmpV
  gemm_raw<u16><<<dim3(6, 64, 8), 256, 0, stream>>>(w_kv, 384, x, tmpV, 4096, 384, flag, flag);
  // 4) dw 3x3 full-res on v-half -> v          (tmpV dead after this)
  dw_full<<<dim3(49152), 256, 0, stream>>>(tmpV, w_kv_dw, 384, v, flag);
  // 5) q1 = W_q @ y
  gemm_raw<u16><<<dim3(6, 16, 8), 256, 0, stream>>>(w_q, 0, y, q1, 1024, 384, flag, flag);
  // 6) q3 = full 3x3 conv(q1)                  (q3 lives in slabBig)
  conv3x3_full<<<dim3(6, 16, 8), 256, 0, stream>>>(w_q_dw, q1, q3, flag);
  // 7) row norms + attention scores + softmax
  rownorm<<<dim3(3072, 2), 256, 0, stream>>>(q3, kp, qn, kn);
  attn_sm<<<dim3(64), 256, 0, stream>>>(q3, kp, qn, kn, temp, flag, attn);
  // 8) aout = attn @ v                         (q3 dead; aout overwrites slabBig)
  applyV<<<dim3(16, 64), 256, 0, stream>>>(attn, v, aout);
  // 9) out = W_proj @ aout -> FP32 output      (khalf staging dead; full 50 MB written)
  gemm_raw<float><<<dim3(6, 64, 8), 256, 0, stream>>>(w_proj, 0, aout, out, 4096, 384,
                                                      flag, flag + 1);
  (void)in_sizes; (void)n_in; (void)out_size; (void)ws_size;
}

// Round 6
// 610.655 us; speedup vs baseline: 2.8248x; 2.8248x over previous
//
#include <hip/hip_runtime.h>

using u16 = unsigned short;
typedef __attribute__((ext_vector_type(8))) short bf16x8;
typedef __attribute__((ext_vector_type(4))) float f32x4;

// ---------- bf16 <-> fp32 ----------
__device__ __forceinline__ float bf2f(u16 u) {
  return __uint_as_float(((unsigned)u) << 16);
}
__device__ __forceinline__ u16 f2bf(float f) {
  unsigned u = __float_as_uint(f);
  u += 0x7FFFu + ((u >> 16) & 1u);  // RNE
  return (u16)(u >> 16);
}
__device__ __forceinline__ float ldr(const void* __restrict__ p, size_t i, int f) {
  return f ? ((const float*)p)[i] : bf2f(((const u16*)p)[i]);
}

// ---------- dtype detect: temperature==1.0 -> bf16 word0=0x3F80, fp32 word0=0x0000
__global__ void detect_dtype(const u16* __restrict__ t, int* __restrict__ flag) {
  if (threadIdx.x == 0) { flag[0] = (t[0] == 0x3F80u) ? 0 : 1; flag[1] = 0; }
}

// ---------- stage 16 elems global->LDS (raw fp32/bf16 -> bf16) ----------
__device__ __forceinline__ void stage16_raw(const void* __restrict__ g, size_t gi,
                                            int f, u16* lp) {
  if (f) {
    const float4* fp4 = (const float4*)((const float*)g + gi);
    float4 x0 = fp4[0], x1 = fp4[1], x2 = fp4[2], x3 = fp4[3];
    union { u16 u[16]; uint4 v[2]; } t;
    t.u[0] = f2bf(x0.x); t.u[1] = f2bf(x0.y); t.u[2] = f2bf(x0.z); t.u[3] = f2bf(x0.w);
    t.u[4] = f2bf(x1.x); t.u[5] = f2bf(x1.y); t.u[6] = f2bf(x1.z); t.u[7] = f2bf(x1.w);
    t.u[8] = f2bf(x2.x); t.u[9] = f2bf(x2.y); t.u[10] = f2bf(x2.z); t.u[11] = f2bf(x2.w);
    t.u[12] = f2bf(x3.x); t.u[13] = f2bf(x3.y); t.u[14] = f2bf(x3.z); t.u[15] = f2bf(x3.w);
    ((uint4*)lp)[0] = t.v[0];
    ((uint4*)lp)[1] = t.v[1];
  } else {
    const uint4* up = (const uint4*)((const u16*)g + gi);
    ((uint4*)lp)[0] = up[0];
    ((uint4*)lp)[1] = up[1];
  }
}

// ---------- MFMA GEMM (TN): C[b] = A(MxK) * B[b](NxK)^T ----------
// A raw (flag), B bf16 k-contiguous. Tile 128x128, BK=32. grid(M/128, N/128, batch).
// TOUT=false: C[b][m][n] (scalar stores); TOUT=true: C[b][n][m] (ushort4 stores, u16 only).
template <typename TC, bool TOUT>
__global__ __launch_bounds__(256) void gemm_tn(
    const void* __restrict__ A, const int* __restrict__ fA,
    const u16* __restrict__ B, TC* __restrict__ C, int M, int N, int K) {
  const int fa = *fA;
  __shared__ u16 As[128][40];
  __shared__ u16 Bs[128][40];
  const int t = threadIdx.x;
  const int bm = blockIdx.x * 128, bn = blockIdx.y * 128;
  const size_t bb = blockIdx.z;
  const int row = t >> 1, seg = (t & 1) * 16;
  const size_t Abase = (size_t)(bm + row) * K + seg;
  const size_t Bbase = ((size_t)bb * N + bn + row) * K + seg;
  const int w = t >> 6, lane = t & 63;
  const int q = lane >> 4, l16 = lane & 15;
  const int mw = (w >> 1) * 64, nw = (w & 1) * 64;
  f32x4 acc[4][4] = {};
  for (int k0 = 0; k0 < K; k0 += 32) {
    stage16_raw(A, Abase + k0, fa, &As[row][seg]);
    {
      const uint4* up = (const uint4*)(B + Bbase + k0);
      *(uint4*)&Bs[row][seg] = up[0];
      *(uint4*)&Bs[row][seg + 8] = up[1];
    }
    __syncthreads();
    bf16x8 af[4], bfr[4];
#pragma unroll
    for (int mt = 0; mt < 4; ++mt)
      af[mt] = *(const bf16x8*)&As[mw + mt * 16 + l16][q * 8];
#pragma unroll
    for (int nt = 0; nt < 4; ++nt)
      bfr[nt] = *(const bf16x8*)&Bs[nw + nt * 16 + l16][q * 8];
#pragma unroll
    for (int mt = 0; mt < 4; ++mt)
#pragma unroll
      for (int nt = 0; nt < 4; ++nt)
        acc[mt][nt] = __builtin_amdgcn_mfma_f32_16x16x32_bf16(
            af[mt], bfr[nt], acc[mt][nt], 0, 0, 0);
    __syncthreads();
  }
  if constexpr (TOUT) {
#pragma unroll
    for (int mt = 0; mt < 4; ++mt)
#pragma unroll
      for (int nt = 0; nt < 4; ++nt) {
        f32x4 f = acc[mt][nt];
        int m0 = bm + mw + mt * 16 + q * 4;
        int n = bn + nw + nt * 16 + l16;
        ushort4 s = make_ushort4(f2bf(f[0]), f2bf(f[1]), f2bf(f[2]), f2bf(f[3]));
        *reinterpret_cast<ushort4*>((u16*)C + ((size_t)bb * N + n) * M + m0) = s;
      }
  } else {
    TC* Cb = C + bb * (size_t)M * N;
#pragma unroll
    for (int mt = 0; mt < 4; ++mt)
#pragma unroll
      for (int nt = 0; nt < 4; ++nt) {
        f32x4 f = acc[mt][nt];
        int m0 = bm + mw + mt * 16 + q * 4;
        int n = bn + nw + nt * 16 + l16;
#pragma unroll
        for (int i = 0; i < 4; ++i) {
          if constexpr (sizeof(TC) == 2)
            Cb[(size_t)(m0 + i) * N + n] = f2bf(f[i]);
          else
            Cb[(size_t)(m0 + i) * N + n] = f[i];
        }
      }
  }
}

// ---------- MFMA full 3x3 conv as GEMM: K = 9 taps x 384, B rows tap-shifted ----------
// Wt: (384, 3456) bf16, k = tap*384+i. q1T: (8, 1024, 384) bf16. C: (8,384,1024) bf16.
__global__ __launch_bounds__(256) void conv_tn(
    const u16* __restrict__ Wt, const u16* __restrict__ q1T, u16* __restrict__ C) {
  __shared__ u16 As[128][40];
  __shared__ u16 Bs[128][40];
  const int t = threadIdx.x;
  const int bm = blockIdx.x * 128, bn = blockIdx.y * 128;
  const size_t bb = blockIdx.z;
  const int row = t >> 1, seg = (t & 1) * 16;
  const int w = t >> 6, lane = t & 63;
  const int q = lane >> 4, l16 = lane & 15;
  const int mw = (w >> 1) * 64, nw = (w & 1) * 64;
  const int n = bn + row, r = n >> 5, c = n & 31;
  f32x4 acc[4][4] = {};
  for (int tap = 0; tap < 9; ++tap) {
    const int dy = tap / 3 - 1, dx = tap % 3 - 1;
    const int rr = r + dy, cc = c + dx;
    const bool ok = (unsigned)rr < 32u && (unsigned)cc < 32u;
    const size_t bsrc =
        ok ? ((size_t)bb * 1024 + rr * 32 + cc) * 384 + seg : 0;
    const size_t asrc = (size_t)(bm + row) * 3456 + tap * 384 + seg;
    for (int i0 = 0; i0 < 384; i0 += 32) {
      {
        const uint4* up = (const uint4*)(Wt + asrc + i0);
        *(uint4*)&As[row][seg] = up[0];
        *(uint4*)&As[row][seg + 8] = up[1];
      }
      if (ok) {
        const uint4* up = (const uint4*)(q1T + bsrc + i0);
        *(uint4*)&Bs[row][seg] = up[0];
        *(uint4*)&Bs[row][seg + 8] = up[1];
      } else {
        uint4 z = make_uint4(0, 0, 0, 0);
        *(uint4*)&Bs[row][seg] = z;
        *(uint4*)&Bs[row][seg + 8] = z;
      }
      __syncthreads();
      bf16x8 af[4], bfr[4];
#pragma unroll
      for (int mt = 0; mt < 4; ++mt)
        af[mt] = *(const bf16x8*)&As[mw + mt * 16 + l16][q * 8];
#pragma unroll
      for (int nt = 0; nt < 4; ++nt)
        bfr[nt] = *(const bf16x8*)&Bs[nw + nt * 16 + l16][q * 8];
#pragma unroll
      for (int mt = 0; mt < 4; ++mt)
#pragma unroll
        for (int nt = 0; nt < 4; ++nt)
          acc[mt][nt] = __builtin_amdgcn_mfma_f32_16x16x32_bf16(
              af[mt], bfr[nt], acc[mt][nt], 0, 0, 0);
      __syncthreads();
    }
  }
  u16* Cb = C + bb * (size_t)(384 * 1024);
#pragma unroll
  for (int mt = 0; mt < 4; ++mt)
#pragma unroll
    for (int nt = 0; nt < 4; ++nt) {
      f32x4 f = acc[mt][nt];
      int m0 = bm + mw + mt * 16 + q * 4;
      int nn = bn + nw + nt * 16 + l16;
#pragma unroll
      for (int i = 0; i < 4; ++i) Cb[(size_t)(m0 + i) * 1024 + nn] = f2bf(f[i]);
    }
}

// ---------- transpose (8,384,N) raw -> (8,N,384) bf16 ----------
__global__ __launch_bounds__(256) void transpose_cn(
    const void* __restrict__ src, const int* __restrict__ fp_,
    u16* __restrict__ dst, int N) {
  const int f = *fp_;
  __shared__ u16 tile[64][72];
  const int n0 = blockIdx.x * 64, c0 = blockIdx.y * 64;
  const size_t b = blockIdx.z;
  const int t = threadIdx.x;
  {
    const int cr = t >> 2, nseg = (t & 3) * 16;
    const size_t gi = ((size_t)b * 384 + c0 + cr) * N + n0 + nseg;
    stage16_raw(src, gi, f, &tile[cr][nseg]);
  }
  __syncthreads();
  {
    const int nr = t >> 2, cseg = (t & 3) * 16;
    union { u16 u[16]; uint4 v[2]; } o;
#pragma unroll
    for (int j = 0; j < 16; ++j) o.u[j] = tile[cseg + j][nr];
    u16* dp = dst + ((size_t)b * N + n0 + nr) * 384 + c0 + cseg;
    *(uint4*)dp = o.v[0];
    *(uint4*)(dp + 8) = o.v[1];
  }
}

// ---------- reorder w_q_dw (384,384,3,3) -> Wt[o][tap*384+i] bf16 ----------
__global__ __launch_bounds__(256) void transpose_wq(
    const void* __restrict__ W, const int* __restrict__ fp_, u16* __restrict__ Wt) {
  int idx = blockIdx.x * 256 + threadIdx.x;
  int o = idx / 3456, rem = idx % 3456;
  int tap = rem / 384, i = rem % 384;
  Wt[idx] = f2bf(ldr(W, (size_t)o * 3456 + (size_t)i * 9 + tap, *fp_));
}

// ---------- depthwise 3x3 full-res; kv (8,768,4096) u16, channel block ch0 ----------
__global__ __launch_bounds__(256) void dw_full(
    const u16* __restrict__ kv, const void* __restrict__ wdw, int ch0,
    u16* __restrict__ dst, const int* __restrict__ fW) {
  const int fw = *fW;
  int idx = blockIdx.x * 256 + threadIdx.x;  // (b*384+c)*4096 + p
  int p = idx & 4095;
  int bc = idx >> 12;
  int c = bc % 384, b = bc / 384;
  int yy = p >> 6, xx = p & 63;
  const u16* s0 = kv + ((size_t)b * 768 + ch0 + c) * 4096;
  float wv[9];
#pragma unroll
  for (int i = 0; i < 9; ++i) wv[i] = ldr(wdw, (size_t)(ch0 + c) * 9 + i, fw);
  float s = 0.f;
#pragma unroll
  for (int dy = -1; dy <= 1; ++dy)
#pragma unroll
    for (int dx = -1; dx <= 1; ++dx) {
      int Y = yy + dy, X = xx + dx;
      if (Y >= 0 && Y < 64 && X >= 0 && X < 64)
        s += wv[(dy + 1) * 3 + (dx + 1)] * bf2f(s0[Y * 64 + X]);
    }
  dst[idx] = f2bf(s);
}

// ---------- depthwise 3x3 + 2x2 mean pool; kv (8,768,4096), channels ch0.. ----------
__global__ __launch_bounds__(256) void dw_pool(
    const u16* __restrict__ kv, const void* __restrict__ wdw, int ch0,
    u16* __restrict__ dst, const int* __restrict__ fW) {
  const int fw = *fW;
  int idx = blockIdx.x * 256 + threadIdx.x;  // (b*384+c)*1024 + pp
  int pp = idx & 1023;
  int bc = idx >> 10;
  int c = bc % 384, b = bc / 384;
  int py = pp >> 5, px = pp & 31;
  const u16* s0 = kv + ((size_t)b * 768 + ch0 + c) * 4096;
  float wv[9];
#pragma unroll
  for (int i = 0; i < 9; ++i) wv[i] = ldr(wdw, (size_t)(ch0 + c) * 9 + i, fw);
  float s = 0.f;
#pragma unroll
  for (int sy = 0; sy < 2; ++sy)
#pragma unroll
    for (int sx = 0; sx < 2; ++sx) {
      int yy = 2 * py + sy, xx = 2 * px + sx;
#pragma unroll
      for (int dy = -1; dy <= 1; ++dy)
#pragma unroll
        for (int dx = -1; dx <= 1; ++dx) {
          int Y = yy + dy, X = xx + dx;
          if (Y >= 0 && Y < 64 && X >= 0 && X < 64)
            s += wv[(dy + 1) * 3 + (dx + 1)] * bf2f(s0[Y * 64 + X]);
        }
    }
  dst[idx] = f2bf(s * 0.25f);
}

// ---------- L2 norms of 1024-length bf16 rows ----------
__global__ __launch_bounds__(256) void rownorm(
    const u16* __restrict__ q3, const u16* __restrict__ kp,
    float* __restrict__ qn, float* __restrict__ kn) {
  const u16* X = (blockIdx.y == 0 ? q3 : kp) + (size_t)blockIdx.x * 1024;
  int t = threadIdx.x;
  ushort4 u = reinterpret_cast<const ushort4*>(X)[t];
  float a = bf2f(u.x), b = bf2f(u.y), c = bf2f(u.z), d = bf2f(u.w);
  float s = a * a + b * b + c * c + d * d;
#pragma unroll
  for (int off = 32; off > 0; off >>= 1) s += __shfl_down(s, off, 64);
  __shared__ float red[4];
  if ((t & 63) == 0) red[t >> 6] = s;
  __syncthreads();
  if (t == 0) {
    float tot = red[0] + red[1] + red[2] + red[3];
    (blockIdx.y == 0 ? qn : kn)[blockIdx.x] = sqrtf(tot);
  }
}

// ---------- attention scores + softmax, one block per (b,h) ----------
__global__ __launch_bounds__(256) void attn_sm(
    const u16* __restrict__ q, const u16* __restrict__ kpool,
    const float* __restrict__ qn, const float* __restrict__ kn,
    const void* __restrict__ temp, const int* __restrict__ fT,
    float* __restrict__ attn) {
  const int ft = *fT;
  __shared__ float qs[48][129];
  __shared__ float ks[48][129];
  __shared__ float at[48][48];
  int bh = blockIdx.x;
  int b = bh >> 3, h = bh & 7;
  int t = threadIdx.x;
  int i0 = (t >> 4) * 3, j0 = (t & 15) * 3;
  const u16* qb = q + ((size_t)b * 384 + h * 48) * 1024;
  const u16* kb = kpool + ((size_t)b * 384 + h * 48) * 1024;
  float acc[3][3] = {};
  for (int n0 = 0; n0 < 1024; n0 += 128) {
    for (int e = t; e < 48 * 32; e += 256) {
      int row = e >> 5, col4 = (e & 31) * 4;
      ushort4 uq = *reinterpret_cast<const ushort4*>(qb + (size_t)row * 1024 + n0 + col4);
      ushort4 uk = *reinterpret_cast<const ushort4*>(kb + (size_t)row * 1024 + n0 + col4);
      qs[row][col4 + 0] = bf2f(uq.x); qs[row][col4 + 1] = bf2f(uq.y);
      qs[row][col4 + 2] = bf2f(uq.z); qs[row][col4 + 3] = bf2f(uq.w);
      ks[row][col4 + 0] = bf2f(uk.x); ks[row][col4 + 1] = bf2f(uk.y);
      ks[row][col4 + 2] = bf2f(uk.z); ks[row][col4 + 3] = bf2f(uk.w);
    }
    __syncthreads();
#pragma unroll 4
    for (int nn = 0; nn < 128; ++nn) {
      float q0 = qs[i0][nn], q1 = qs[i0 + 1][nn], q2 = qs[i0 + 2][nn];
      float k0 = ks[j0][nn], k1 = ks[j0 + 1][nn], k2 = ks[j0 + 2][nn];
      acc[0][0] += q0 * k0; acc[0][1] += q0 * k1; acc[0][2] += q0 * k2;
      acc[1][0] += q1 * k0; acc[1][1] += q1 * k1; acc[1][2] += q1 * k2;
      acc[2][0] += q2 * k0; acc[2][1] += q2 * k1; acc[2][2] += q2 * k2;
    }
    __syncthreads();
  }
  float tv = ldr(temp, h, ft);
#pragma unroll
  for (int ii = 0; ii < 3; ++ii)
#pragma unroll
    for (int jj = 0; jj < 3; ++jj) {
      int i = i0 + ii, j = j0 + jj;
      float sc = tv / (fmaxf(qn[b * 384 + h * 48 + i], 1e-12f) *
                       fmaxf(kn[b * 384 + h * 48 + j], 1e-12f));
      at[i][j] = acc[ii][jj] * sc;
    }
  __syncthreads();
  if (t < 48) {
    float mx = -3.4e38f;
#pragma unroll
    for (int j = 0; j < 48; ++j) mx = fmaxf(mx, at[t][j]);
    float sum = 0.f;
    float e[48];
#pragma unroll
    for (int j = 0; j < 48; ++j) { e[j] = expf(at[t][j] - mx); sum += e[j]; }
    float inv = 1.f / sum;
    float* ao = attn + (size_t)bh * 2304 + t * 48;
#pragma unroll
    for (int j = 0; j < 48; ++j) ao[j] = e[j] * inv;
  }
}

// ---------- aoutT[b][p][c] = sum_d attn[b,h,c,d] * v[b,h*48+d,p] ----------
__global__ __launch_bounds__(256) void applyV(
    const float* __restrict__ attn, const u16* __restrict__ v,
    u16* __restrict__ aoutT) {
  __shared__ float at[48][48];
  int bh = blockIdx.y;
  int b = bh >> 3, h = bh & 7;
  int t = threadIdx.x;
  for (int e = t; e < 2304; e += 256) at[e / 48][e % 48] = attn[(size_t)bh * 2304 + e];
  __syncthreads();
  int p = blockIdx.x * 256 + t;
  const u16* vb = v + ((size_t)b * 384 + h * 48) * 4096 + p;
  float acc[48] = {};
#pragma unroll
  for (int c4 = 0; c4 < 48; c4 += 4) {
    float v0 = bf2f(vb[(size_t)(c4 + 0) * 4096]);
    float v1 = bf2f(vb[(size_t)(c4 + 1) * 4096]);
    float v2 = bf2f(vb[(size_t)(c4 + 2) * 4096]);
    float v3 = bf2f(vb[(size_t)(c4 + 3) * 4096]);
#pragma unroll
    for (int c0 = 0; c0 < 48; ++c0) {
      float4 a = *reinterpret_cast<const float4*>(&at[c0][c4]);
      acc[c0] += a.x * v0 + a.y * v1 + a.z * v2 + a.w * v3;
    }
  }
  union { u16 u[48]; uint4 v4[6]; } o;
#pragma unroll
  for (int c0 = 0; c0 < 48; ++c0) o.u[c0] = f2bf(acc[c0]);
  u16* dp = aoutT + ((size_t)b * 4096 + p) * 384 + h * 48;
#pragma unroll
  for (int j = 0; j < 6; ++j) *(uint4*)(dp + j * 8) = o.v4[j];
}

extern "C" void kernel_launch(void* const* d_in, const int* in_sizes, int n_in,
                              void* d_out, int out_size, void* d_ws, size_t ws_size,
                              hipStream_t stream) {
  const void* x       = d_in[0];  // (8,384,64,64)
  const void* y       = d_in[1];  // (8,384,32,32)
  const void* w_kv    = d_in[2];  // (768,384)
  const void* w_kv_dw = d_in[3];  // (768,9)
  const void* w_q     = d_in[4];  // (384,384)
  const void* w_q_dw  = d_in[5];  // (384,384,3,3)
  const void* w_proj  = d_in[6];  // (384,384)
  const void* temp    = d_in[7];  // (8)

  // ---- workspace ~57 MB ----
  char* base = (char*)d_ws;
  size_t off = 0;
  auto alloc = [&](size_t bytes) {
    void* p = base + off;
    off += (bytes + 255) & ~(size_t)255;
    return p;
  };
  int*   flag = (int*)  alloc(8);
  float* qn   = (float*)alloc(3072ull * 4);
  float* kn   = (float*)alloc(3072ull * 4);
  float* attn = (float*)alloc(147456ull * 4);
  u16*   S1   = (u16*)  alloc(12582912ull * 2);  // xT -> v
  u16*   S2   = (u16*)  alloc(12582912ull * 2);  // yT/q1T/Wt/q3 -> aoutT
  u16*   kp   = (u16*)  alloc(3145728ull * 2);

  u16* xT    = S1;                 // (8,4096,384)
  u16* v     = S1;                 // (8,384,4096)  after xT dead
  u16* yT    = S2;                 // (8,1024,384)
  u16* q1T   = S2 + 3145728;       // (8,1024,384)
  u16* Wt    = S2 + 6291456;       // (384,3456)
  u16* q3    = S2 + 7618560;       // (8,384,1024)
  u16* aoutT = S2;                 // (8,4096,384)  after all above dead
  u16* kv    = (u16*)d_out;        // (8,768,4096) staging; dead before proj

  // 0) dtype detect
  detect_dtype<<<1, 64, 0, stream>>>((const u16*)temp, flag);
  // 1) transposes: x->xT, y->yT, w_q_dw->Wt
  transpose_cn<<<dim3(64, 6, 8), 256, 0, stream>>>(x, flag, xT, 4096);
  transpose_cn<<<dim3(16, 6, 8), 256, 0, stream>>>(y, flag, yT, 1024);
  transpose_wq<<<dim3(5184), 256, 0, stream>>>(w_q_dw, flag, Wt);
  // 2) kv = W_kv @ x  (M=768, N=4096, K=384) -> d_out staging (bf16)
  gemm_tn<u16, false><<<dim3(6, 32, 8), 256, 0, stream>>>(
      w_kv, flag, xT, kv, 768, 4096, 384);
  // 3) depthwise: k-half -> pool -> kp ; v-half full-res -> v (xT dead)
  dw_pool<<<dim3(12288), 256, 0, stream>>>(kv, w_kv_dw, 0, kp, flag);
  dw_full<<<dim3(49152), 256, 0, stream>>>(kv, w_kv_dw, 384, v, flag);
  // 4) q1 = W_q @ y -> q1T (transposed out, M=384, N=1024)
  gemm_tn<u16, true><<<dim3(3, 8, 8), 256, 0, stream>>>(
      w_q, flag, yT, q1T, 384, 1024, 384);
  // 5) q3 = full 3x3 conv (MFMA, K=3456)
  conv_tn<<<dim3(3, 8, 8), 256, 0, stream>>>(Wt, q1T, q3);
  // 6) norms + attention + softmax
  rownorm<<<dim3(3072, 2), 256, 0, stream>>>(q3, kp, qn, kn);
  attn_sm<<<dim3(64), 256, 0, stream>>>(q3, kp, qn, kn, temp, flag, attn);
  // 7) aoutT = attn @ v  (writes n-major; S2 contents dead)
  applyV<<<dim3(16, 64), 256, 0, stream>>>(attn, v, aoutT);
  // 8) out = W_proj @ aout -> fp32 d_out (M=384, N=4096)
  gemm_tn<float, false><<<dim3(3, 32, 8), 256, 0, stream>>>(
      w_proj, flag, aoutT, (float*)d_out, 384, 4096, 384);
  (void)in_sizes; (void)n_in; (void)out_size; (void)ws_size;
}

// Round 7
// 520.821 us; speedup vs baseline: 3.3120x; 1.1725x over previous
//
#include <hip/hip_runtime.h>

using u16 = unsigned short;
typedef __attribute__((ext_vector_type(8))) short bf16x8;
typedef __attribute__((ext_vector_type(4))) float f32x4;

// ---------- bf16 <-> fp32 ----------
__device__ __forceinline__ float bf2f(u16 u) {
  return __uint_as_float(((unsigned)u) << 16);
}
__device__ __forceinline__ u16 f2bf(float f) {
  unsigned u = __float_as_uint(f);
  u += 0x7FFFu + ((u >> 16) & 1u);  // RNE
  return (u16)(u >> 16);
}
__device__ __forceinline__ float ldr(const void* __restrict__ p, size_t i, int f) {
  return f ? ((const float*)p)[i] : bf2f(((const u16*)p)[i]);
}

// ---------- dtype detect: temperature==1.0 -> bf16 word0=0x3F80, fp32 word0=0x0000
__global__ void detect_dtype(const u16* __restrict__ t, int* __restrict__ flag) {
  if (threadIdx.x == 0) { flag[0] = (t[0] == 0x3F80u) ? 0 : 1; flag[1] = 0; }
}

// ---------- stage 16 elems global->LDS (raw fp32/bf16 -> bf16) ----------
__device__ __forceinline__ void stage16_raw(const void* __restrict__ g, size_t gi,
                                            int f, u16* lp) {
  if (f) {
    const float4* fp4 = (const float4*)((const float*)g + gi);
    float4 x0 = fp4[0], x1 = fp4[1], x2 = fp4[2], x3 = fp4[3];
    union { u16 u[16]; uint4 v[2]; } t;
    t.u[0] = f2bf(x0.x); t.u[1] = f2bf(x0.y); t.u[2] = f2bf(x0.z); t.u[3] = f2bf(x0.w);
    t.u[4] = f2bf(x1.x); t.u[5] = f2bf(x1.y); t.u[6] = f2bf(x1.z); t.u[7] = f2bf(x1.w);
    t.u[8] = f2bf(x2.x); t.u[9] = f2bf(x2.y); t.u[10] = f2bf(x2.z); t.u[11] = f2bf(x2.w);
    t.u[12] = f2bf(x3.x); t.u[13] = f2bf(x3.y); t.u[14] = f2bf(x3.z); t.u[15] = f2bf(x3.w);
    ((uint4*)lp)[0] = t.v[0];
    ((uint4*)lp)[1] = t.v[1];
  } else {
    const uint4* up = (const uint4*)((const u16*)g + gi);
    ((uint4*)lp)[0] = up[0];
    ((uint4*)lp)[1] = up[1];
  }
}

// ---------- MFMA GEMM (TN): C[b] = A(MxK) * B[b](NxK)^T ----------
// A raw (flag), B bf16 k-contiguous. Tile 128x128, BK=32. grid(M/128, N/128, batch).
// TOUT=false: C[b][m][n] (scalar stores); TOUT=true: C[b][n][m] (ushort4 stores, u16 only).
template <typename TC, bool TOUT>
__global__ __launch_bounds__(256) void gemm_tn(
    const void* __restrict__ A, const int* __restrict__ fA,
    const u16* __restrict__ B, TC* __restrict__ C, int M, int N, int K) {
  const int fa = *fA;
  __shared__ u16 As[128][40];
  __shared__ u16 Bs[128][40];
  const int t = threadIdx.x;
  const int bm = blockIdx.x * 128, bn = blockIdx.y * 128;
  const size_t bb = blockIdx.z;
  const int row = t >> 1, seg = (t & 1) * 16;
  const size_t Abase = (size_t)(bm + row) * K + seg;
  const size_t Bbase = ((size_t)bb * N + bn + row) * K + seg;
  const int w = t >> 6, lane = t & 63;
  const int q = lane >> 4, l16 = lane & 15;
  const int mw = (w >> 1) * 64, nw = (w & 1) * 64;
  f32x4 acc[4][4] = {};
  for (int k0 = 0; k0 < K; k0 += 32) {
    stage16_raw(A, Abase + k0, fa, &As[row][seg]);
    {
      const uint4* up = (const uint4*)(B + Bbase + k0);
      *(uint4*)&Bs[row][seg] = up[0];
      *(uint4*)&Bs[row][seg + 8] = up[1];
    }
    __syncthreads();
    bf16x8 af[4], bfr[4];
#pragma unroll
    for (int mt = 0; mt < 4; ++mt)
      af[mt] = *(const bf16x8*)&As[mw + mt * 16 + l16][q * 8];
#pragma unroll
    for (int nt = 0; nt < 4; ++nt)
      bfr[nt] = *(const bf16x8*)&Bs[nw + nt * 16 + l16][q * 8];
#pragma unroll
    for (int mt = 0; mt < 4; ++mt)
#pragma unroll
      for (int nt = 0; nt < 4; ++nt)
        acc[mt][nt] = __builtin_amdgcn_mfma_f32_16x16x32_bf16(
            af[mt], bfr[nt], acc[mt][nt], 0, 0, 0);
    __syncthreads();
  }
  if constexpr (TOUT) {
#pragma unroll
    for (int mt = 0; mt < 4; ++mt)
#pragma unroll
      for (int nt = 0; nt < 4; ++nt) {
        f32x4 f = acc[mt][nt];
        int m0 = bm + mw + mt * 16 + q * 4;
        int n = bn + nw + nt * 16 + l16;
        ushort4 s = make_ushort4(f2bf(f[0]), f2bf(f[1]), f2bf(f[2]), f2bf(f[3]));
        *reinterpret_cast<ushort4*>((u16*)C + ((size_t)bb * N + n) * M + m0) = s;
      }
  } else {
    TC* Cb = C + bb * (size_t)M * N;
#pragma unroll
    for (int mt = 0; mt < 4; ++mt)
#pragma unroll
      for (int nt = 0; nt < 4; ++nt) {
        f32x4 f = acc[mt][nt];
        int m0 = bm + mw + mt * 16 + q * 4;
        int n = bn + nw + nt * 16 + l16;
#pragma unroll
        for (int i = 0; i < 4; ++i) {
          if constexpr (sizeof(TC) == 2)
            Cb[(size_t)(m0 + i) * N + n] = f2bf(f[i]);
          else
            Cb[(size_t)(m0 + i) * N + n] = f[i];
        }
      }
  }
}

// ---------- MFMA full 3x3 conv as GEMM: K = 9 taps x 384, B rows tap-shifted ----------
// Wt: (384, 3456) bf16, k = tap*384+i. q1T: (8, 1024, 384) bf16. C: (8,384,1024) bf16.
__global__ __launch_bounds__(256) void conv_tn(
    const u16* __restrict__ Wt, const u16* __restrict__ q1T, u16* __restrict__ C) {
  __shared__ u16 As[128][40];
  __shared__ u16 Bs[128][40];
  const int t = threadIdx.x;
  const int bm = blockIdx.x * 128, bn = blockIdx.y * 128;
  const size_t bb = blockIdx.z;
  const int row = t >> 1, seg = (t & 1) * 16;
  const int w = t >> 6, lane = t & 63;
  const int q = lane >> 4, l16 = lane & 15;
  const int mw = (w >> 1) * 64, nw = (w & 1) * 64;
  const int n = bn + row, r = n >> 5, c = n & 31;
  f32x4 acc[4][4] = {};
  for (int tap = 0; tap < 9; ++tap) {
    const int dy = tap / 3 - 1, dx = tap % 3 - 1;
    const int rr = r + dy, cc = c + dx;
    const bool ok = (unsigned)rr < 32u && (unsigned)cc < 32u;
    const size_t bsrc =
        ok ? ((size_t)bb * 1024 + rr * 32 + cc) * 384 + seg : 0;
    const size_t asrc = (size_t)(bm + row) * 3456 + tap * 384 + seg;
    for (int i0 = 0; i0 < 384; i0 += 32) {
      {
        const uint4* up = (const uint4*)(Wt + asrc + i0);
        *(uint4*)&As[row][seg] = up[0];
        *(uint4*)&As[row][seg + 8] = up[1];
      }
      if (ok) {
        const uint4* up = (const uint4*)(q1T + bsrc + i0);
        *(uint4*)&Bs[row][seg] = up[0];
        *(uint4*)&Bs[row][seg + 8] = up[1];
      } else {
        uint4 z = make_uint4(0, 0, 0, 0);
        *(uint4*)&Bs[row][seg] = z;
        *(uint4*)&Bs[row][seg + 8] = z;
      }
      __syncthreads();
      bf16x8 af[4], bfr[4];
#pragma unroll
      for (int mt = 0; mt < 4; ++mt)
        af[mt] = *(const bf16x8*)&As[mw + mt * 16 + l16][q * 8];
#pragma unroll
      for (int nt = 0; nt < 4; ++nt)
        bfr[nt] = *(const bf16x8*)&Bs[nw + nt * 16 + l16][q * 8];
#pragma unroll
      for (int mt = 0; mt < 4; ++mt)
#pragma unroll
        for (int nt = 0; nt < 4; ++nt)
          acc[mt][nt] = __builtin_amdgcn_mfma_f32_16x16x32_bf16(
              af[mt], bfr[nt], acc[mt][nt], 0, 0, 0);
      __syncthreads();
    }
  }
  u16* Cb = C + bb * (size_t)(384 * 1024);
#pragma unroll
  for (int mt = 0; mt < 4; ++mt)
#pragma unroll
    for (int nt = 0; nt < 4; ++nt) {
      f32x4 f = acc[mt][nt];
      int m0 = bm + mw + mt * 16 + q * 4;
      int nn = bn + nw + nt * 16 + l16;
#pragma unroll
      for (int i = 0; i < 4; ++i) Cb[(size_t)(m0 + i) * 1024 + nn] = f2bf(f[i]);
    }
}

// ---------- transpose (8,384,N) raw -> (8,N,384) bf16 ----------
__global__ __launch_bounds__(256) void transpose_cn(
    const void* __restrict__ src, const int* __restrict__ fp_,
    u16* __restrict__ dst, int N) {
  const int f = *fp_;
  __shared__ u16 tile[64][72];
  const int n0 = blockIdx.x * 64, c0 = blockIdx.y * 64;
  const size_t b = blockIdx.z;
  const int t = threadIdx.x;
  {
    const int cr = t >> 2, nseg = (t & 3) * 16;
    const size_t gi = ((size_t)b * 384 + c0 + cr) * N + n0 + nseg;
    stage16_raw(src, gi, f, &tile[cr][nseg]);
  }
  __syncthreads();
  {
    const int nr = t >> 2, cseg = (t & 3) * 16;
    union { u16 u[16]; uint4 v[2]; } o;
#pragma unroll
    for (int j = 0; j < 16; ++j) o.u[j] = tile[cseg + j][nr];
    u16* dp = dst + ((size_t)b * N + n0 + nr) * 384 + c0 + cseg;
    *(uint4*)dp = o.v[0];
    *(uint4*)(dp + 8) = o.v[1];
  }
}

// ---------- reorder w_q_dw (384,384,3,3) -> Wt[o][tap*384+i] bf16 ----------
__global__ __launch_bounds__(256) void transpose_wq(
    const void* __restrict__ W, const int* __restrict__ fp_, u16* __restrict__ Wt) {
  int idx = blockIdx.x * 256 + threadIdx.x;
  int o = idx / 3456, rem = idx % 3456;
  int tap = rem / 384, i = rem % 384;
  Wt[idx] = f2bf(ldr(W, (size_t)o * 3456 + (size_t)i * 9 + tap, *fp_));
}

// ---------- depthwise 3x3 full-res; kv (8,768,4096) u16, channel block ch0 ----------
__global__ __launch_bounds__(256) void dw_full(
    const u16* __restrict__ kv, const void* __restrict__ wdw, int ch0,
    u16* __restrict__ dst, const int* __restrict__ fW) {
  const int fw = *fW;
  int idx = blockIdx.x * 256 + threadIdx.x;  // (b*384+c)*4096 + p
  int p = idx & 4095;
  int bc = idx >> 12;
  int c = bc % 384, b = bc / 384;
  int yy = p >> 6, xx = p & 63;
  const u16* s0 = kv + ((size_t)b * 768 + ch0 + c) * 4096;
  float wv[9];
#pragma unroll
  for (int i = 0; i < 9; ++i) wv[i] = ldr(wdw, (size_t)(ch0 + c) * 9 + i, fw);
  float s = 0.f;
#pragma unroll
  for (int dy = -1; dy <= 1; ++dy)
#pragma unroll
    for (int dx = -1; dx <= 1; ++dx) {
      int Y = yy + dy, X = xx + dx;
      if (Y >= 0 && Y < 64 && X >= 0 && X < 64)
        s += wv[(dy + 1) * 3 + (dx + 1)] * bf2f(s0[Y * 64 + X]);
    }
  dst[idx] = f2bf(s);
}

// ---------- depthwise 3x3 + 2x2 mean pool; kv (8,768,4096), channels ch0.. ----------
__global__ __launch_bounds__(256) void dw_pool(
    const u16* __restrict__ kv, const void* __restrict__ wdw, int ch0,
    u16* __restrict__ dst, const int* __restrict__ fW) {
  const int fw = *fW;
  int idx = blockIdx.x * 256 + threadIdx.x;  // (b*384+c)*1024 + pp
  int pp = idx & 1023;
  int bc = idx >> 10;
  int c = bc % 384, b = bc / 384;
  int py = pp >> 5, px = pp & 31;
  const u16* s0 = kv + ((size_t)b * 768 + ch0 + c) * 4096;
  float wv[9];
#pragma unroll
  for (int i = 0; i < 9; ++i) wv[i] = ldr(wdw, (size_t)(ch0 + c) * 9 + i, fw);
  float s = 0.f;
#pragma unroll
  for (int sy = 0; sy < 2; ++sy)
#pragma unroll
    for (int sx = 0; sx < 2; ++sx) {
      int yy = 2 * py + sy, xx = 2 * px + sx;
#pragma unroll
      for (int dy = -1; dy <= 1; ++dy)
#pragma unroll
        for (int dx = -1; dx <= 1; ++dx) {
          int Y = yy + dy, X = xx + dx;
          if (Y >= 0 && Y < 64 && X >= 0 && X < 64)
            s += wv[(dy + 1) * 3 + (dx + 1)] * bf2f(s0[Y * 64 + X]);
        }
    }
  dst[idx] = f2bf(s * 0.25f);
}

// ---------- L2 norms of 1024-length bf16 rows ----------
__global__ __launch_bounds__(256) void rownorm(
    const u16* __restrict__ q3, const u16* __restrict__ kp,
    float* __restrict__ qn, float* __restrict__ kn) {
  const u16* X = (blockIdx.y == 0 ? q3 : kp) + (size_t)blockIdx.x * 1024;
  int t = threadIdx.x;
  ushort4 u = reinterpret_cast<const ushort4*>(X)[t];
  float a = bf2f(u.x), b = bf2f(u.y), c = bf2f(u.z), d = bf2f(u.w);
  float s = a * a + b * b + c * c + d * d;
#pragma unroll
  for (int off = 32; off > 0; off >>= 1) s += __shfl_down(s, off, 64);
  __shared__ float red[4];
  if ((t & 63) == 0) red[t >> 6] = s;
  __syncthreads();
  if (t == 0) {
    float tot = red[0] + red[1] + red[2] + red[3];
    (blockIdx.y == 0 ? qn : kn)[blockIdx.x] = sqrtf(tot);
  }
}

// ---------- attention scores + softmax, one block per (b,h) ----------
__global__ __launch_bounds__(256) void attn_sm(
    const u16* __restrict__ q, const u16* __restrict__ kpool,
    const float* __restrict__ qn, const float* __restrict__ kn,
    const void* __restrict__ temp, const int* __restrict__ fT,
    float* __restrict__ attn) {
  const int ft = *fT;
  __shared__ float qs[48][129];
  __shared__ float ks[48][129];
  __shared__ float at[48][48];
  int bh = blockIdx.x;
  int b = bh >> 3, h = bh & 7;
  int t = threadIdx.x;
  int i0 = (t >> 4) * 3, j0 = (t & 15) * 3;
  const u16* qb = q + ((size_t)b * 384 + h * 48) * 1024;
  const u16* kb = kpool + ((size_t)b * 384 + h * 48) * 1024;
  float acc[3][3] = {};
  for (int n0 = 0; n0 < 1024; n0 += 128) {
    for (int e = t; e < 48 * 32; e += 256) {
      int row = e >> 5, col4 = (e & 31) * 4;
      ushort4 uq = *reinterpret_cast<const ushort4*>(qb + (size_t)row * 1024 + n0 + col4);
      ushort4 uk = *reinterpret_cast<const ushort4*>(kb + (size_t)row * 1024 + n0 + col4);
      qs[row][col4 + 0] = bf2f(uq.x); qs[row][col4 + 1] = bf2f(uq.y);
      qs[row][col4 + 2] = bf2f(uq.z); qs[row][col4 + 3] = bf2f(uq.w);
      ks[row][col4 + 0] = bf2f(uk.x); ks[row][col4 + 1] = bf2f(uk.y);
      ks[row][col4 + 2] = bf2f(uk.z); ks[row][col4 + 3] = bf2f(uk.w);
    }
    __syncthreads();
#pragma unroll 4
    for (int nn = 0; nn < 128; ++nn) {
      float q0 = qs[i0][nn], q1 = qs[i0 + 1][nn], q2 = qs[i0 + 2][nn];
      float k0 = ks[j0][nn], k1 = ks[j0 + 1][nn], k2 = ks[j0 + 2][nn];
      acc[0][0] += q0 * k0; acc[0][1] += q0 * k1; acc[0][2] += q0 * k2;
      acc[1][0] += q1 * k0; acc[1][1] += q1 * k1; acc[1][2] += q1 * k2;
      acc[2][0] += q2 * k0; acc[2][1] += q2 * k1; acc[2][2] += q2 * k2;
    }
    __syncthreads();
  }
  float tv = ldr(temp, h, ft);
#pragma unroll
  for (int ii = 0; ii < 3; ++ii)
#pragma unroll
    for (int jj = 0; jj < 3; ++jj) {
      int i = i0 + ii, j = j0 + jj;
      float sc = tv / (fmaxf(qn[b * 384 + h * 48 + i], 1e-12f) *
                       fmaxf(kn[b * 384 + h * 48 + j], 1e-12f));
      at[i][j] = acc[ii][jj] * sc;
    }
  __syncthreads();
  if (t < 48) {
    float mx = -3.4e38f;
#pragma unroll
    for (int j = 0; j < 48; ++j) mx = fmaxf(mx, at[t][j]);
    float sum = 0.f;
    float e[48];
#pragma unroll
    for (int j = 0; j < 48; ++j) { e[j] = expf(at[t][j] - mx); sum += e[j]; }
    float inv = 1.f / sum;
    float* ao = attn + (size_t)bh * 2304 + t * 48;
#pragma unroll
    for (int j = 0; j < 48; ++j) ao[j] = e[j] * inv;
  }
}

// ---------- aoutT[b][p][c] = sum_d attn[b,h,c,d] * v[b,h*48+d,p] ----------
// grid (8 p-blocks, 4 c-blocks, 64 bh); thread: 2 p, 12 c. Low-VGPR, high occupancy.
__global__ __launch_bounds__(256) void applyV(
    const float* __restrict__ attn, const u16* __restrict__ v,
    u16* __restrict__ aoutT) {
  __shared__ float at[12][48];
  int bh = blockIdx.z;
  int b = bh >> 3, h = bh & 7;
  int cb = blockIdx.y;
  int t = threadIdx.x;
  for (int e = t; e < 12 * 48; e += 256)
    at[e / 48][e % 48] = attn[((size_t)bh * 48 + cb * 12 + e / 48) * 48 + (e % 48)];
  __syncthreads();
  int p = blockIdx.x * 512 + t * 2;
  const u16* vb = v + ((size_t)b * 384 + h * 48) * 4096 + p;
  float acc[12][2] = {};
#pragma unroll 4
  for (int d = 0; d < 48; ++d) {
    ushort2 u = *reinterpret_cast<const ushort2*>(vb + (size_t)d * 4096);
    float v0 = bf2f(u.x), v1 = bf2f(u.y);
#pragma unroll
    for (int j = 0; j < 12; ++j) {
      float a = at[j][d];
      acc[j][0] += a * v0;
      acc[j][1] += a * v1;
    }
  }
#pragma unroll
  for (int i = 0; i < 2; ++i) {
    union { u16 u[12]; ushort4 v4[3]; } o;
#pragma unroll
    for (int j = 0; j < 12; ++j) o.u[j] = f2bf(acc[j][i]);
    u16* dp = aoutT + ((size_t)b * 4096 + p + i) * 384 + h * 48 + cb * 12;
#pragma unroll
    for (int s = 0; s < 3; ++s) *reinterpret_cast<ushort4*>(dp + s * 4) = o.v4[s];
  }
}

extern "C" void kernel_launch(void* const* d_in, const int* in_sizes, int n_in,
                              void* d_out, int out_size, void* d_ws, size_t ws_size,
                              hipStream_t stream) {
  const void* x       = d_in[0];  // (8,384,64,64)
  const void* y       = d_in[1];  // (8,384,32,32)
  const void* w_kv    = d_in[2];  // (768,384)
  const void* w_kv_dw = d_in[3];  // (768,9)
  const void* w_q     = d_in[4];  // (384,384)
  const void* w_q_dw  = d_in[5];  // (384,384,3,3)
  const void* w_proj  = d_in[6];  // (384,384)
  const void* temp    = d_in[7];  // (8)

  // ---- workspace ~57 MB ----
  char* base = (char*)d_ws;
  size_t off = 0;
  auto alloc = [&](size_t bytes) {
    void* p = base + off;
    off += (bytes + 255) & ~(size_t)255;
    return p;
  };
  int*   flag = (int*)  alloc(8);
  float* qn   = (float*)alloc(3072ull * 4);
  float* kn   = (float*)alloc(3072ull * 4);
  float* attn = (float*)alloc(147456ull * 4);
  u16*   S1   = (u16*)  alloc(12582912ull * 2);  // xT -> v
  u16*   S2   = (u16*)  alloc(12582912ull * 2);  // yT/q1T/Wt/q3 -> aoutT
  u16*   kp   = (u16*)  alloc(3145728ull * 2);

  u16* xT    = S1;                 // (8,4096,384)
  u16* v     = S1;                 // (8,384,4096)  after xT dead
  u16* yT    = S2;                 // (8,1024,384)
  u16* q1T   = S2 + 3145728;       // (8,1024,384)
  u16* Wt    = S2 + 6291456;       // (384,3456)
  u16* q3    = S2 + 7618560;       // (8,384,1024)
  u16* aoutT = S2;                 // (8,4096,384)  after all above dead
  u16* kv    = (u16*)d_out;        // (8,768,4096) staging; dead before proj

  // 0) dtype detect
  detect_dtype<<<1, 64, 0, stream>>>((const u16*)temp, flag);
  // 1) transposes: x->xT, y->yT, w_q_dw->Wt
  transpose_cn<<<dim3(64, 6, 8), 256, 0, stream>>>(x, flag, xT, 4096);
  transpose_cn<<<dim3(16, 6, 8), 256, 0, stream>>>(y, flag, yT, 1024);
  transpose_wq<<<dim3(5184), 256, 0, stream>>>(w_q_dw, flag, Wt);
  // 2) kv = W_kv @ x  (M=768, N=4096, K=384) -> d_out staging (bf16)
  gemm_tn<u16, false><<<dim3(6, 32, 8), 256, 0, stream>>>(
      w_kv, flag, xT, kv, 768, 4096, 384);
  // 3) depthwise: k-half -> pool -> kp ; v-half full-res -> v (xT dead)
  dw_pool<<<dim3(12288), 256, 0, stream>>>(kv, w_kv_dw, 0, kp, flag);
  dw_full<<<dim3(49152), 256, 0, stream>>>(kv, w_kv_dw, 384, v, flag);
  // 4) q1 = W_q @ y -> q1T (transposed out, M=384, N=1024)
  gemm_tn<u16, true><<<dim3(3, 8, 8), 256, 0, stream>>>(
      w_q, flag, yT, q1T, 384, 1024, 384);
  // 5) q3 = full 3x3 conv (MFMA, K=3456)
  conv_tn<<<dim3(3, 8, 8), 256, 0, stream>>>(Wt, q1T, q3);
  // 6) norms + attention + softmax
  rownorm<<<dim3(3072, 2), 256, 0, stream>>>(q3, kp, qn, kn);
  attn_sm<<<dim3(64), 256, 0, stream>>>(q3, kp, qn, kn, temp, flag, attn);
  // 7) aoutT = attn @ v  (writes n-major; S2 contents dead)
  applyV<<<dim3(8, 4, 64), 256, 0, stream>>>(attn, v, aoutT);
  // 8) out = W_proj @ aout -> fp32 d_out (M=384, N=4096)
  gemm_tn<float, false><<<dim3(3, 32, 8), 256, 0, stream>>>(
      w_proj, flag, aoutT, (float*)d_out, 384, 4096, 384);
  (void)in_sizes; (void)n_in; (void)out_size; (void)ws_size;
}